// Round 6
// baseline (231.189 us; speedup 1.0000x reference)
//
#include <hip/hip_runtime.h>
#include <hip/hip_bf16.h>
#include <stdint.h>
#include <stddef.h>

// MatchLSTMAttention: B=64, T=2048, inp_p=inp_q=out=512
// out[b] = concat(input_p[b], z[b]); z = softmax_t(w . tanh(prq[b] + iq[b,t] @ Wq^T)) @ iq[b]

typedef __attribute__((ext_vector_type(8))) short short8;
typedef __attribute__((ext_vector_type(8))) unsigned short ushort8v;
typedef __attribute__((ext_vector_type(4))) float f32x4;

__device__ __forceinline__ short8 cvt8(float4 a, float4 b) {
    union { __hip_bfloat162 h[4]; short8 s; } u;
    u.h[0] = __float22bfloat162_rn(make_float2(a.x, a.y));
    u.h[1] = __float22bfloat162_rn(make_float2(a.z, a.w));
    u.h[2] = __float22bfloat162_rn(make_float2(b.x, b.y));
    u.h[3] = __float22bfloat162_rn(make_float2(b.z, b.w));
    return u.s;
}

__device__ __forceinline__ float bf2f(unsigned short u) {
    unsigned v = (unsigned)u << 16;
    return __builtin_bit_cast(float, v);
}

__device__ __forceinline__ void gload_lds16(const void* g, void* l) {
    __builtin_amdgcn_global_load_lds(
        (const __attribute__((address_space(1))) unsigned int*)g,
        (__attribute__((address_space(3))) unsigned int*)l, 16, 0, 0);
}

// ---------- kernel Z: zero logits ----------
__global__ __launch_bounds__(256) void k_zero(float* __restrict__ p) {
    int i = (blockIdx.x * 256 + threadIdx.x) * 4;
    *(float4*)(p + i) = make_float4(0.f, 0.f, 0.f, 0.f);
}

// ---------- fp32 -> bf16 streaming convert (8 elems/thread) ----------
__global__ __launch_bounds__(256) void k_convert8(const float* __restrict__ src,
                                                  unsigned short* __restrict__ dst) {
    size_t i = ((size_t)blockIdx.x * 256 + threadIdx.x) * 8;
    float4 a = *(const float4*)(src + i);
    float4 b = *(const float4*)(src + i + 4);
    *(short8*)(dst + i) = cvt8(a, b);
}

// ---------- kernel 1: prq[b,o] = ip.Wp^T + h.Wr^T + bp + bq + br ----------
__global__ __launch_bounds__(256) void k_prq(
        const float* __restrict__ ip, const float* __restrict__ h,
        const float* __restrict__ Wp, const float* __restrict__ Wr,
        const float* __restrict__ bp, const float* __restrict__ bq,
        const float* __restrict__ br, float* __restrict__ prq) {
    __shared__ float ip_lds[64][68];
    __shared__ float h_lds[64][68];
    __shared__ float wp_lds[8][68];
    __shared__ float wr_lds[8][68];
    const int tid = threadIdx.x;
    const int o0 = blockIdx.x * 8;
    const int bb = tid >> 3;
    const int oo = tid & 7;
    float acc0 = 0.f, acc1 = 0.f;
    const int lrow = tid >> 2;
    const int lcol = (tid & 3) * 16;
    for (int kc = 0; kc < 512; kc += 64) {
        #pragma unroll
        for (int j = 0; j < 16; j += 4) {
            float4 v = *(const float4*)(ip + lrow * 512 + kc + lcol + j);
            ip_lds[lrow][lcol + j] = v.x; ip_lds[lrow][lcol + j + 1] = v.y;
            ip_lds[lrow][lcol + j + 2] = v.z; ip_lds[lrow][lcol + j + 3] = v.w;
            float4 u = *(const float4*)(h + lrow * 512 + kc + lcol + j);
            h_lds[lrow][lcol + j] = u.x; h_lds[lrow][lcol + j + 1] = u.y;
            h_lds[lrow][lcol + j + 2] = u.z; h_lds[lrow][lcol + j + 3] = u.w;
        }
        if (tid < 128) {
            int r = tid >> 4, c = (tid & 15) * 4;
            float4 v = *(const float4*)(Wp + (size_t)(o0 + r) * 512 + kc + c);
            wp_lds[r][c] = v.x; wp_lds[r][c + 1] = v.y; wp_lds[r][c + 2] = v.z; wp_lds[r][c + 3] = v.w;
        } else {
            int t2 = tid - 128;
            int r = t2 >> 4, c = (t2 & 15) * 4;
            float4 v = *(const float4*)(Wr + (size_t)(o0 + r) * 512 + kc + c);
            wr_lds[r][c] = v.x; wr_lds[r][c + 1] = v.y; wr_lds[r][c + 2] = v.z; wr_lds[r][c + 3] = v.w;
        }
        __syncthreads();
        #pragma unroll 4
        for (int k = 0; k < 64; ++k) {
            float wpv = wp_lds[oo][k], wrv = wr_lds[oo][k];
            acc0 += ip_lds[bb][k] * wpv + h_lds[bb][k] * wrv;
            acc1 += ip_lds[bb + 32][k] * wpv + h_lds[bb + 32][k] * wrv;
        }
        __syncthreads();
    }
    const int o = o0 + oo;
    float base = bp[o] + bq[o] + br[o];
    prq[bb * 512 + o] = acc0 + base;
    prq[(bb + 32) * 512 + o] = acc1 + base;
}

// ---------- kernel 2 (bf16-A path): pure m97 GEMM + fused tanh/w epilogue ----------
// 128x128 tile, 4 waves (64x64), BK=32, BOTH operands via global_load_lds w=16
// (pre-swizzled sources, linear LDS dest), double-buffered, counted vmcnt(4),
// two raw barriers per step. Source is L3-resident bf16 (written by k_convert8).
__global__ __launch_bounds__(256, 2) void k_gq16(
        const unsigned short* __restrict__ iqb, const unsigned short* __restrict__ Wq_bf,
        const float* __restrict__ prq, const float* __restrict__ wv,
        float* __restrict__ logits) {
    __shared__ unsigned short A2[2][4096];    // 2 x 8 KB, 64B rows, chunk ^= (row>>1)&3
    __shared__ unsigned short B2[2][4096];
    __shared__ float w_lds[128];
    __shared__ float prq_lds[128];
    __shared__ float red[2][128];

    const int tid = threadIdx.x;
    const int bid = blockIdx.x;
    const int orig = (bid & 7) * 512 + (bid >> 3);   // XCD-chunked (4096 % 8 == 0)
    const int m0 = (orig >> 2) * 128;
    const int n0 = (orig & 3) * 128;
    const int b = m0 >> 11;

    if (tid < 128) {
        w_lds[tid] = wv[n0 + tid];
        prq_lds[tid] = prq[b * 512 + n0 + tid];
    }

    const int lane = tid & 63;
    const int wave = tid >> 6;
    const int wm = wave >> 1;
    const int wn = wave & 1;
    const int r16 = lane & 15;
    const int cc = lane >> 4;
    const int swz = ((cc ^ ((r16 >> 1) & 3)) << 3);

    // pre-swizzled global sources: stored chunk s holds global chunk s ^ ((row>>1)&3)
    const unsigned short *as0, *as1, *bs0, *bs1;
    {
        int t0 = tid, row0 = t0 >> 2, g0 = (t0 & 3) ^ ((row0 >> 1) & 3);
        as0 = iqb + (size_t)(m0 + row0) * 512 + (g0 << 3);
        bs0 = Wq_bf + (size_t)(n0 + row0) * 512 + (g0 << 3);
        int t1 = 256 + tid, row1 = t1 >> 2, g1 = (t1 & 3) ^ ((row1 >> 1) & 3);
        as1 = iqb + (size_t)(m0 + row1) * 512 + (g1 << 3);
        bs1 = Wq_bf + (size_t)(n0 + row1) * 512 + (g1 << 3);
    }
    char* abase = (char*)A2;
    char* bbase = (char*)B2;

#define STAGE(K, BUF)                                                      \
    {                                                                      \
        gload_lds16(as0 + (K), abase + (BUF) * 8192 + wave * 1024);        \
        gload_lds16(as1 + (K), abase + (BUF) * 8192 + 4096 + wave * 1024); \
        gload_lds16(bs0 + (K), bbase + (BUF) * 8192 + wave * 1024);        \
        gload_lds16(bs1 + (K), bbase + (BUF) * 8192 + 4096 + wave * 1024); \
    }

    f32x4 acc[4][4];
    #pragma unroll
    for (int i = 0; i < 4; ++i)
        #pragma unroll
        for (int j = 0; j < 4; ++j) acc[i][j] = (f32x4){0.f, 0.f, 0.f, 0.f};

    STAGE(0, 0);
    #pragma unroll 2
    for (int s = 0; s < 16; ++s) {
        if (s < 15) {
            STAGE((s + 1) * 32, (s + 1) & 1);
            asm volatile("s_waitcnt vmcnt(4)" ::: "memory");   // stage(s) landed; stage(s+1) in flight
        } else {
            asm volatile("s_waitcnt vmcnt(0)" ::: "memory");
        }
        __builtin_amdgcn_s_barrier();
        const unsigned short* Ab = &A2[s & 1][0];
        const unsigned short* Bb = &B2[s & 1][0];
        short8 af0 = *(const short8*)&Ab[(wm * 64 +  0 + r16) * 32 + swz];
        short8 af1 = *(const short8*)&Ab[(wm * 64 + 16 + r16) * 32 + swz];
        short8 af2 = *(const short8*)&Ab[(wm * 64 + 32 + r16) * 32 + swz];
        short8 af3 = *(const short8*)&Ab[(wm * 64 + 48 + r16) * 32 + swz];
        #pragma unroll
        for (int nf = 0; nf < 4; ++nf) {
            short8 bfr = *(const short8*)&Bb[(wn * 64 + nf * 16 + r16) * 32 + swz];
            acc[0][nf] = __builtin_amdgcn_mfma_f32_16x16x32_bf16(af0, bfr, acc[0][nf], 0, 0, 0);
            acc[1][nf] = __builtin_amdgcn_mfma_f32_16x16x32_bf16(af1, bfr, acc[1][nf], 0, 0, 0);
            acc[2][nf] = __builtin_amdgcn_mfma_f32_16x16x32_bf16(af2, bfr, acc[2][nf], 0, 0, 0);
            acc[3][nf] = __builtin_amdgcn_mfma_f32_16x16x32_bf16(af3, bfr, acc[3][nf], 0, 0, 0);
        }
        asm volatile("s_waitcnt lgkmcnt(0)" ::: "memory");     // all ds_reads of this buf done
        __builtin_amdgcn_s_barrier();                          // safe to overwrite next iter
    }
#undef STAGE

    // epilogue: partial logit = sum over this block's 128 cols of w[c]*tanh(acc+prq[c])
    float part[4][4];
    #pragma unroll
    for (int mf = 0; mf < 4; ++mf)
        #pragma unroll
        for (int j = 0; j < 4; ++j) part[mf][j] = 0.f;

    #pragma unroll
    for (int nf = 0; nf < 4; ++nf) {
        int c = wn * 64 + nf * 16 + r16;
        float wc = w_lds[c];
        float pc = prq_lds[c];
        #pragma unroll
        for (int mf = 0; mf < 4; ++mf) {
            #pragma unroll
            for (int j = 0; j < 4; ++j) {
                float x = acc[mf][nf][j] + pc;
                float e = __expf(2.f * x);               // fast tanh: 1 - 2/(e^2x + 1)
                part[mf][j] += wc * (1.f - 2.f / (e + 1.f));
            }
        }
    }
    #pragma unroll
    for (int mf = 0; mf < 4; ++mf)
        #pragma unroll
        for (int j = 0; j < 4; ++j) {
            float v = part[mf][j];
            v += __shfl_xor(v, 1);
            v += __shfl_xor(v, 2);
            v += __shfl_xor(v, 4);
            v += __shfl_xor(v, 8);
            part[mf][j] = v;
        }
    if (r16 == 0) {
        #pragma unroll
        for (int mf = 0; mf < 4; ++mf)
            #pragma unroll
            for (int j = 0; j < 4; ++j)
                red[wn][wm * 64 + mf * 16 + cc * 4 + j] = part[mf][j];
    }
    __syncthreads();
    if (tid < 128)
        atomicAdd(&logits[m0 + tid], red[0][tid] + red[1][tid]);
}

// ---------- kernel 2 (fallback fp32-A path, R5 verbatim) ----------
__global__ __launch_bounds__(256, 3) void k_gq32(
        const float* __restrict__ iq, const unsigned short* __restrict__ Wq_bf,
        const float* __restrict__ prq, const float* __restrict__ wv,
        float* __restrict__ logits) {
    __shared__ unsigned short A2[2][4096];
    __shared__ unsigned short B2[2][4096];
    __shared__ float w_lds[128];
    __shared__ float prq_lds[128];
    __shared__ float red[2][128];

    const int tid = threadIdx.x;
    const int bid = blockIdx.x;
    const int orig = (bid & 7) * 512 + (bid >> 3);
    const int m0 = (orig >> 2) * 128;
    const int n0 = (orig & 3) * 128;
    const int b = m0 >> 11;

    if (tid < 128) {
        w_lds[tid] = wv[n0 + tid];
        prq_lds[tid] = prq[b * 512 + n0 + tid];
    }

    const int lane = tid & 63;
    const int wave = tid >> 6;
    const int wm = wave >> 1;
    const int wn = wave & 1;
    const int r16 = lane & 15;
    const int cc = lane >> 4;
    const int swz = ((cc ^ ((r16 >> 1) & 3)) << 3);

    const int ar0 = tid >> 2, ac0 = tid & 3;
    const int ar1 = 64 + (tid >> 2), ac1 = tid & 3;
    const float* asrc0 = iq + (size_t)(m0 + ar0) * 512 + ac0 * 8;
    const float* asrc1 = iq + (size_t)(m0 + ar1) * 512 + ac1 * 8;
    const int aoff0 = ar0 * 32 + ((ac0 ^ ((ar0 >> 1) & 3)) << 3);
    const int aoff1 = ar1 * 32 + ((ac1 ^ ((ar1 >> 1) & 3)) << 3);

    const int brw0 = tid >> 2, bsw0 = (tid & 3) ^ ((brw0 >> 1) & 3);
    const int brw1 = 64 + (tid >> 2);
    const int bsw1 = (tid & 3) ^ ((brw1 >> 1) & 3);
    const unsigned short* bsrc0 = Wq_bf + (size_t)(n0 + brw0) * 512 + (bsw0 << 3);
    const unsigned short* bsrc1 = Wq_bf + (size_t)(n0 + brw1) * 512 + (bsw1 << 3);

    f32x4 acc[4][4];
    #pragma unroll
    for (int i = 0; i < 4; ++i)
        #pragma unroll
        for (int j = 0; j < 4; ++j) acc[i][j] = (f32x4){0.f, 0.f, 0.f, 0.f};

    float4 ra0, ra1, ra2, ra3;

    gload_lds16(bsrc0, (char*)&B2[0][0] + wave * 1024);
    gload_lds16(bsrc1, (char*)&B2[0][0] + 4096 + wave * 1024);
    ra0 = *(const float4*)(asrc0);
    ra1 = *(const float4*)(asrc0 + 4);
    ra2 = *(const float4*)(asrc1);
    ra3 = *(const float4*)(asrc1 + 4);
    *(short8*)&A2[0][aoff0] = cvt8(ra0, ra1);
    *(short8*)&A2[0][aoff1] = cvt8(ra2, ra3);
    asm volatile("s_waitcnt vmcnt(0) lgkmcnt(0)" ::: "memory");
    __builtin_amdgcn_sched_barrier(0);
    __builtin_amdgcn_s_barrier();

#define PHASE(K, C, PF)                                                          \
    {                                                                            \
        if (PF) {                                                                \
            gload_lds16(bsrc0 + (K) + 32, (char*)&B2[(C) ^ 1][0] + wave * 1024); \
            gload_lds16(bsrc1 + (K) + 32, (char*)&B2[(C) ^ 1][0] + 4096 + wave * 1024); \
            ra0 = *(const float4*)(asrc0 + (K) + 32);                            \
            ra1 = *(const float4*)(asrc0 + (K) + 36);                            \
            ra2 = *(const float4*)(asrc1 + (K) + 32);                            \
            ra3 = *(const float4*)(asrc1 + (K) + 36);                            \
        }                                                                        \
        short8 af0 = *(const short8*)&A2[C][(wm * 64 +  0 + r16) * 32 + swz];    \
        short8 af1 = *(const short8*)&A2[C][(wm * 64 + 16 + r16) * 32 + swz];    \
        short8 af2 = *(const short8*)&A2[C][(wm * 64 + 32 + r16) * 32 + swz];    \
        short8 af3 = *(const short8*)&A2[C][(wm * 64 + 48 + r16) * 32 + swz];    \
        _Pragma("unroll")                                                        \
        for (int nf = 0; nf < 4; ++nf) {                                         \
            short8 bfr = *(const short8*)&B2[C][(wn * 64 + nf * 16 + r16) * 32 + swz]; \
            acc[0][nf] = __builtin_amdgcn_mfma_f32_16x16x32_bf16(af0, bfr, acc[0][nf], 0, 0, 0); \
            acc[1][nf] = __builtin_amdgcn_mfma_f32_16x16x32_bf16(af1, bfr, acc[1][nf], 0, 0, 0); \
            acc[2][nf] = __builtin_amdgcn_mfma_f32_16x16x32_bf16(af2, bfr, acc[2][nf], 0, 0, 0); \
            acc[3][nf] = __builtin_amdgcn_mfma_f32_16x16x32_bf16(af3, bfr, acc[3][nf], 0, 0, 0); \
        }                                                                        \
        if (PF) {                                                                \
            *(short8*)&A2[(C) ^ 1][aoff0] = cvt8(ra0, ra1);                      \
            *(short8*)&A2[(C) ^ 1][aoff1] = cvt8(ra2, ra3);                      \
        }                                                                        \
        asm volatile("s_waitcnt vmcnt(0) lgkmcnt(0)" ::: "memory");              \
        __builtin_amdgcn_sched_barrier(0);                                       \
        __builtin_amdgcn_s_barrier();                                            \
    }

    for (int kk = 0; kk < 512; kk += 64) {
        PHASE(kk, 0, 1);
        PHASE(kk + 32, 1, (kk + 64) < 512);
    }
#undef PHASE

    float part[4][4];
    #pragma unroll
    for (int mf = 0; mf < 4; ++mf)
        #pragma unroll
        for (int j = 0; j < 4; ++j) part[mf][j] = 0.f;

    #pragma unroll
    for (int nf = 0; nf < 4; ++nf) {
        int c = wn * 64 + nf * 16 + r16;
        float wc = w_lds[c];
        float pc = prq_lds[c];
        #pragma unroll
        for (int mf = 0; mf < 4; ++mf) {
            #pragma unroll
            for (int j = 0; j < 4; ++j) {
                float x = acc[mf][nf][j] + pc;
                float e = __expf(2.f * x);
                part[mf][j] += wc * (1.f - 2.f / (e + 1.f));
            }
        }
    }
    #pragma unroll
    for (int mf = 0; mf < 4; ++mf)
        #pragma unroll
        for (int j = 0; j < 4; ++j) {
            float v = part[mf][j];
            v += __shfl_xor(v, 1);
            v += __shfl_xor(v, 2);
            v += __shfl_xor(v, 4);
            v += __shfl_xor(v, 8);
            part[mf][j] = v;
        }
    if (r16 == 0) {
        #pragma unroll
        for (int mf = 0; mf < 4; ++mf)
            #pragma unroll
            for (int j = 0; j < 4; ++j)
                red[wn][wm * 64 + mf * 16 + cc * 4 + j] = part[mf][j];
    }
    __syncthreads();
    if (tid < 128)
        atomicAdd(&logits[m0 + tid], red[0][tid] + red[1][tid]);
}

// ---------- kernel 3: softmax stats per b; copy input_p -> out; zero z ----------
__global__ __launch_bounds__(256) void k_stats(const float* __restrict__ logits,
                                               const float* __restrict__ ip,
                                               float* __restrict__ out,
                                               float* __restrict__ stats) {
    const int b = blockIdx.x, tid = threadIdx.x;
    __shared__ float sm[256];
    float m = -1e30f;
    for (int i = tid; i < 2048; i += 256) m = fmaxf(m, logits[b * 2048 + i]);
    sm[tid] = m;
    __syncthreads();
    for (int s = 128; s > 0; s >>= 1) {
        if (tid < s) sm[tid] = fmaxf(sm[tid], sm[tid + s]);
        __syncthreads();
    }
    float bmax = sm[0];
    __syncthreads();
    float ssum = 0.f;
    for (int i = tid; i < 2048; i += 256) ssum += __expf(logits[b * 2048 + i] - bmax);
    sm[tid] = ssum;
    __syncthreads();
    for (int s = 128; s > 0; s >>= 1) {
        if (tid < s) sm[tid] += sm[tid + s];
        __syncthreads();
    }
    if (tid == 0) { stats[b * 2] = bmax; stats[b * 2 + 1] = sm[0]; }
    out[b * 1024 + tid] = ip[b * 512 + tid];
    out[b * 1024 + 256 + tid] = ip[b * 512 + 256 + tid];
    out[b * 1024 + 512 + tid] = 0.f;
    out[b * 1024 + 768 + tid] = 0.f;
}

// ---------- kernel 4 (bf16): z[b,q] += sum_t alpha[b,t] * iq_bf[b,t,q] ----------
#define TC 128
__global__ __launch_bounds__(256) void k_z16(const float* __restrict__ logits,
                                             const float* __restrict__ stats,
                                             const unsigned short* __restrict__ iqb,
                                             float* __restrict__ out) {
    const int blk = blockIdx.x;
    const int b = blk >> 4;
    const int c = blk & 15;
    const int tid = threadIdx.x;
    __shared__ float al[TC];
    const float bmax = stats[b * 2];
    const float inv = 1.f / stats[b * 2 + 1];
    if (tid < TC) al[tid] = __expf(logits[b * 2048 + c * TC + tid] - bmax) * inv;
    __syncthreads();
    const int q = tid * 2;
    float ax = 0.f, ay = 0.f;
    const unsigned short* base = iqb + ((size_t)b * 2048 + (size_t)c * TC) * 512 + q;
    #pragma unroll 4
    for (int t = 0; t < TC; ++t) {
        ushort2 v = *(const ushort2*)(base + (size_t)t * 512);
        float a = al[t];
        ax += a * bf2f(v.x);
        ay += a * bf2f(v.y);
    }
    atomicAdd(&out[b * 1024 + 512 + q], ax);
    atomicAdd(&out[b * 1024 + 512 + q + 1], ay);
}

// ---------- kernel 4 (fp32 fallback) ----------
__global__ __launch_bounds__(256) void k_z32(const float* __restrict__ logits,
                                             const float* __restrict__ stats,
                                             const float* __restrict__ iq,
                                             float* __restrict__ out) {
    const int blk = blockIdx.x;
    const int b = blk >> 4;
    const int c = blk & 15;
    const int tid = threadIdx.x;
    __shared__ float al[TC];
    const float bmax = stats[b * 2];
    const float inv = 1.f / stats[b * 2 + 1];
    if (tid < TC) al[tid] = __expf(logits[b * 2048 + c * TC + tid] - bmax) * inv;
    __syncthreads();
    const int q = tid * 2;
    float ax = 0.f, ay = 0.f;
    const float* base = iq + ((size_t)b * 2048 + (size_t)c * TC) * 512 + q;
    #pragma unroll 4
    for (int t = 0; t < TC; ++t) {
        float2 v = *(const float2*)(base + (size_t)t * 512);
        float a = al[t];
        ax += a * v.x;
        ay += a * v.y;
    }
    atomicAdd(&out[b * 1024 + 512 + q], ax);
    atomicAdd(&out[b * 1024 + 512 + q + 1], ay);
}

extern "C" void kernel_launch(void* const* d_in, const int* in_sizes, int n_in,
                              void* d_out, int out_size, void* d_ws, size_t ws_size,
                              hipStream_t stream) {
    const float* input_p = (const float*)d_in[0];
    const float* input_q = (const float*)d_in[1];
    const float* h_tm1   = (const float*)d_in[2];
    const float* Wp      = (const float*)d_in[3];
    const float* bp      = (const float*)d_in[4];
    const float* Wq      = (const float*)d_in[5];
    const float* bq      = (const float*)d_in[6];
    const float* Wr      = (const float*)d_in[7];
    const float* br      = (const float*)d_in[8];
    const float* wv      = (const float*)d_in[9];
    float* out = (float*)d_out;

    char* ws = (char*)d_ws;
    unsigned short* Wq_bf = (unsigned short*)ws;            // 512 KB
    float* prq    = (float*)(ws + 512 * 1024);              // 128 KB
    float* logits = (float*)(ws + 640 * 1024);              // 512 KB
    float* stats  = (float*)(ws + 1152 * 1024);             // 512 B
    unsigned short* iq_bf = (unsigned short*)(ws + 2 * 1024 * 1024);  // 134.25 MB

    const size_t need = 2ull * 1024 * 1024 + 134217728ull;

    k_zero<<<dim3(128), dim3(256), 0, stream>>>(logits);
    k_convert8<<<dim3(128), dim3(256), 0, stream>>>(Wq, Wq_bf);
    k_prq<<<dim3(64), dim3(256), 0, stream>>>(input_p, h_tm1, Wp, Wr, bp, bq, br, prq);

    if (ws_size >= need) {
        k_convert8<<<dim3(32768), dim3(256), 0, stream>>>(input_q, iq_bf);
        k_gq16<<<dim3(4096), dim3(256), 0, stream>>>(iq_bf, Wq_bf, prq, wv, logits);
        k_stats<<<dim3(64), dim3(256), 0, stream>>>(logits, input_p, out, stats);
        k_z16<<<dim3(64 * 16), dim3(256), 0, stream>>>(logits, stats, iq_bf, out);
    } else {
        k_gq32<<<dim3(4096), dim3(256), 0, stream>>>(input_q, Wq_bf, prq, wv, logits);
        k_stats<<<dim3(64), dim3(256), 0, stream>>>(logits, input_p, out, stats);
        k_z32<<<dim3(64 * 16), dim3(256), 0, stream>>>(logits, stats, input_q, out);
    }
}

// Round 7
// 224.297 us; speedup vs baseline: 1.0307x; 1.0307x over previous
//
#include <hip/hip_runtime.h>
#include <hip/hip_bf16.h>
#include <stdint.h>
#include <stddef.h>

// MatchLSTMAttention: B=64, T=2048, inp_p=inp_q=out=512
// out[b] = concat(input_p[b], z[b]); z = softmax_t(w . tanh(prq[b] + iq[b,t] @ Wq^T)) @ iq[b]
// Single-pass design: one fused kernel reads iq ONCE; A-panel in LDS reused for z.

typedef __attribute__((ext_vector_type(8))) short short8;
typedef __attribute__((ext_vector_type(8))) unsigned short ushort8v;
typedef __attribute__((ext_vector_type(4))) float f32x4;

__device__ __forceinline__ unsigned short f2bf(float f) {
    unsigned int u = __builtin_bit_cast(unsigned int, f);
    return (unsigned short)((u + 0x7FFFu + ((u >> 16) & 1u)) >> 16);  // RNE
}

__device__ __forceinline__ uint2 cvt4(float4 a) {
    union { __hip_bfloat162 h[2]; uint2 v; } u;
    u.h[0] = __float22bfloat162_rn(make_float2(a.x, a.y));
    u.h[1] = __float22bfloat162_rn(make_float2(a.z, a.w));
    return u.v;
}

__device__ __forceinline__ float bf2f(unsigned short u) {
    unsigned v = (unsigned)u << 16;
    return __builtin_bit_cast(float, v);
}

__device__ __forceinline__ void gload_lds16(const void* g, void* l) {
    __builtin_amdgcn_global_load_lds(
        (const __attribute__((address_space(1))) unsigned int*)g,
        (__attribute__((address_space(3))) unsigned int*)l, 16, 0, 0);
}

// ---------- kernel 0: Wq fp32 -> bf16 ----------
__global__ __launch_bounds__(256) void k_convert8(const float* __restrict__ src,
                                                  unsigned short* __restrict__ dst) {
    size_t i = ((size_t)blockIdx.x * 256 + threadIdx.x) * 8;
    float4 a = *(const float4*)(src + i);
    float4 b = *(const float4*)(src + i + 4);
    uint2 lo = cvt4(a), hi = cvt4(b);
    union { uint2 u[2]; short8 s; } p;
    p.u[0] = lo; p.u[1] = hi;
    *(short8*)(dst + i) = p.s;
}

// ---------- kernel 1: prq[b,o] = ip.Wp^T + h.Wr^T + bp + bq + br ----------
__global__ __launch_bounds__(256) void k_prq(
        const float* __restrict__ ip, const float* __restrict__ h,
        const float* __restrict__ Wp, const float* __restrict__ Wr,
        const float* __restrict__ bp, const float* __restrict__ bq,
        const float* __restrict__ br, float* __restrict__ prq) {
    __shared__ float ip_lds[64][68];
    __shared__ float h_lds[64][68];
    __shared__ float wp_lds[8][68];
    __shared__ float wr_lds[8][68];
    const int tid = threadIdx.x;
    const int o0 = blockIdx.x * 8;
    const int bb = tid >> 3;
    const int oo = tid & 7;
    float acc0 = 0.f, acc1 = 0.f;
    const int lrow = tid >> 2;
    const int lcol = (tid & 3) * 16;
    for (int kc = 0; kc < 512; kc += 64) {
        #pragma unroll
        for (int j = 0; j < 16; j += 4) {
            float4 v = *(const float4*)(ip + lrow * 512 + kc + lcol + j);
            ip_lds[lrow][lcol + j] = v.x; ip_lds[lrow][lcol + j + 1] = v.y;
            ip_lds[lrow][lcol + j + 2] = v.z; ip_lds[lrow][lcol + j + 3] = v.w;
            float4 u = *(const float4*)(h + lrow * 512 + kc + lcol + j);
            h_lds[lrow][lcol + j] = u.x; h_lds[lrow][lcol + j + 1] = u.y;
            h_lds[lrow][lcol + j + 2] = u.z; h_lds[lrow][lcol + j + 3] = u.w;
        }
        if (tid < 128) {
            int r = tid >> 4, c = (tid & 15) * 4;
            float4 v = *(const float4*)(Wp + (size_t)(o0 + r) * 512 + kc + c);
            wp_lds[r][c] = v.x; wp_lds[r][c + 1] = v.y; wp_lds[r][c + 2] = v.z; wp_lds[r][c + 3] = v.w;
        } else {
            int t2 = tid - 128;
            int r = t2 >> 4, c = (t2 & 15) * 4;
            float4 v = *(const float4*)(Wr + (size_t)(o0 + r) * 512 + kc + c);
            wr_lds[r][c] = v.x; wr_lds[r][c + 1] = v.y; wr_lds[r][c + 2] = v.z; wr_lds[r][c + 3] = v.w;
        }
        __syncthreads();
        #pragma unroll 4
        for (int k = 0; k < 64; ++k) {
            float wpv = wp_lds[oo][k], wrv = wr_lds[oo][k];
            acc0 += ip_lds[bb][k] * wpv + h_lds[bb][k] * wrv;
            acc1 += ip_lds[bb + 32][k] * wpv + h_lds[bb + 32][k] * wrv;
        }
        __syncthreads();
    }
    const int o = o0 + oo;
    float base = bp[o] + bq[o] + br[o];
    prq[bb * 512 + o] = acc0 + base;
    prq[(bb + 32) * 512 + o] = acc1 + base;
}

// ---------- fused kernel: GEMM(64x512x512) + tanh/w logits + online-softmax + z partial ----------
// 512 thr (8 waves, 2m x 4n, wave tile 32x128). A panel 16 slices [64][32] bf16 in LDS
// (written once, reused by z-phase). B double-buffered via global_load_lds (pre-swizzled
// source). Counted-vmcnt 2-barrier pipeline (R6 discipline). Per-block outputs:
// (m, s) and z_partial[512] -> combined by k_comb.
union ZB { unsigned short B[2][16384]; float zp[8][512]; };

__global__ __launch_bounds__(512, 2) void k_fused(
        const float* __restrict__ iq, const unsigned short* __restrict__ Wq_bf,
        const float* __restrict__ prq, const float* __restrict__ wv,
        float* __restrict__ zp_g, float* __restrict__ ms_g) {
    __shared__ unsigned short A_p[16][2064];   // 64.5 KB (16-ushort pad per slice)
    __shared__ ZB sB;                          // 64 KB (B dbuf) / 16 KB (zp) time-shared
    __shared__ float w_lds[512];
    __shared__ float prq_lds[512];
    __shared__ float red[4][64];
    __shared__ float e_lds[64];

    const int tid = threadIdx.x;
    const int bid = blockIdx.x;                // 2048 blocks; 32 per b
    const int m0 = bid * 64;
    const int b = bid >> 5;

    w_lds[tid] = wv[tid];
    prq_lds[tid] = prq[b * 512 + tid];

    const int lane = tid & 63;
    const int wave = tid >> 6;                 // 0..7
    const int wm = wave >> 2;                  // 0..1 (m half: 32 rows)
    const int wn = wave & 3;                   // 0..3 (n quarter: 128 cols)
    const int r16 = lane & 15;
    const int cc = lane >> 4;
    const int swz = ((cc ^ ((r16 >> 1) & 3)) << 3);

    // A staging: per thread 4 floats of one row's 32-k slice.
    const int arow = tid >> 3;                 // 0..63
    const int afg = tid & 7;                   // 4-float group
    const float* asrc = iq + (size_t)(m0 + arow) * 512 + afg * 4;
    const int adst_off = arow * 32 + ((((afg >> 1)) ^ ((arow >> 1) & 3)) << 3) + (afg & 1) * 4;

    // B staging: pre-swizzled global source; linear LDS dest (4 calls x 8 KB).
    const unsigned short *bsrc0, *bsrc1, *bsrc2, *bsrc3;
    {
        int c0 = tid,        r0 = c0 >> 2, s0 = (c0 & 3) ^ ((r0 >> 1) & 3);
        int c1 = 512 + tid,  r1 = c1 >> 2, s1 = (c1 & 3) ^ ((r1 >> 1) & 3);
        int c2 = 1024 + tid, r2 = c2 >> 2, s2 = (c2 & 3) ^ ((r2 >> 1) & 3);
        int c3 = 1536 + tid, r3 = c3 >> 2, s3 = (c3 & 3) ^ ((r3 >> 1) & 3);
        bsrc0 = Wq_bf + (size_t)r0 * 512 + (s0 << 3);
        bsrc1 = Wq_bf + (size_t)r1 * 512 + (s1 << 3);
        bsrc2 = Wq_bf + (size_t)r2 * 512 + (s2 << 3);
        bsrc3 = Wq_bf + (size_t)r3 * 512 + (s3 << 3);
    }

#define BSTAGE(KT, BUF)                                                             \
    gload_lds16(bsrc0 + (KT) * 32, (char*)&sB.B[BUF][0] + 0 * 8192 + wave * 1024);  \
    gload_lds16(bsrc1 + (KT) * 32, (char*)&sB.B[BUF][0] + 1 * 8192 + wave * 1024);  \
    gload_lds16(bsrc2 + (KT) * 32, (char*)&sB.B[BUF][0] + 2 * 8192 + wave * 1024);  \
    gload_lds16(bsrc3 + (KT) * 32, (char*)&sB.B[BUF][0] + 3 * 8192 + wave * 1024);

    f32x4 acc[2][8];
    #pragma unroll
    for (int i = 0; i < 2; ++i)
        #pragma unroll
        for (int j = 0; j < 8; ++j) acc[i][j] = (f32x4){0.f, 0.f, 0.f, 0.f};

    float4 raA, raB;

    // ---- prologue: slice 0 + issue slice 1 ----
    raA = *(const float4*)(asrc);              // A(0)
    BSTAGE(0, 0);
    asm volatile("s_waitcnt vmcnt(4)" ::: "memory");       // A(0) regs landed
    *(uint2*)&A_p[0][adst_off] = cvt4(raA);
    asm volatile("s_waitcnt lgkmcnt(0)" ::: "memory");
    __builtin_amdgcn_s_barrier();
    raA = *(const float4*)(asrc + 32);         // A(1)
    BSTAGE(1, 1);
    asm volatile("s_waitcnt vmcnt(5)" ::: "memory");       // B(0) landed
    __builtin_amdgcn_s_barrier();

#define ITER(KT, RC, RN)                                                                  \
    {                                                                                     \
        const unsigned short* Ab = &A_p[KT][0];                                           \
        const unsigned short* Bb = &sB.B[(KT) & 1][0];                                    \
        short8 af0 = *(const short8*)&Ab[(wm * 32 + r16) * 32 + swz];                     \
        short8 af1 = *(const short8*)&Ab[(wm * 32 + 16 + r16) * 32 + swz];                \
        _Pragma("unroll")                                                                 \
        for (int nf = 0; nf < 8; ++nf) {                                                  \
            short8 bfr = *(const short8*)&Bb[(wn * 128 + nf * 16 + r16) * 32 + swz];      \
            acc[0][nf] = __builtin_amdgcn_mfma_f32_16x16x32_bf16(af0, bfr, acc[0][nf], 0, 0, 0); \
            acc[1][nf] = __builtin_amdgcn_mfma_f32_16x16x32_bf16(af1, bfr, acc[1][nf], 0, 0, 0); \
        }                                                                                 \
        if ((KT) < 15) {                                                                  \
            asm volatile("s_waitcnt vmcnt(4)" ::: "memory");   /* A(KT+1) regs landed */  \
            *(uint2*)&A_p[(KT) + 1][adst_off] = cvt4(RC);                                 \
            asm volatile("s_waitcnt lgkmcnt(0)" ::: "memory");                            \
            __builtin_amdgcn_s_barrier();      /* buf reads done + panel write visible */ \
            if ((KT) < 14) {                                                              \
                RN = *(const float4*)(asrc + ((KT) + 2) * 32);                            \
                BSTAGE((KT) + 2, (KT) & 1);                                               \
                asm volatile("s_waitcnt vmcnt(5)" ::: "memory");  /* B(KT+1) landed */    \
            } else {                                                                      \
                asm volatile("s_waitcnt vmcnt(0)" ::: "memory");                          \
            }                                                                             \
            __builtin_amdgcn_s_barrier();                                                 \
        }                                                                                 \
    }

    for (int kt = 0; kt < 16; kt += 2) {
        ITER(kt, raA, raB);
        ITER(kt + 1, raB, raA);
    }
#undef ITER
#undef BSTAGE

    // ---- logits epilogue: l_t = sum_c w[c]*tanh(acc + prq[c]) ----
    float part[2][4];
    #pragma unroll
    for (int mf = 0; mf < 2; ++mf)
        #pragma unroll
        for (int j = 0; j < 4; ++j) part[mf][j] = 0.f;

    #pragma unroll
    for (int nf = 0; nf < 8; ++nf) {
        int c = wn * 128 + nf * 16 + r16;
        float wc = w_lds[c];
        float pc = prq_lds[c];
        #pragma unroll
        for (int mf = 0; mf < 2; ++mf) {
            #pragma unroll
            for (int j = 0; j < 4; ++j) {
                float x = acc[mf][nf][j] + pc;
                float e = __expf(2.f * x);               // fast tanh
                part[mf][j] += wc * (1.f - 2.f / (e + 1.f));
            }
        }
    }
    #pragma unroll
    for (int mf = 0; mf < 2; ++mf)
        #pragma unroll
        for (int j = 0; j < 4; ++j) {
            float v = part[mf][j];
            v += __shfl_xor(v, 1);
            v += __shfl_xor(v, 2);
            v += __shfl_xor(v, 4);
            v += __shfl_xor(v, 8);
            part[mf][j] = v;
        }
    if (r16 == 0) {
        #pragma unroll
        for (int mf = 0; mf < 2; ++mf)
            #pragma unroll
            for (int j = 0; j < 4; ++j)
                red[wn][wm * 32 + mf * 16 + cc * 4 + j] = part[mf][j];
    }
    __syncthreads();

    // ---- softmax partial (wave 0: 64 t's) ----
    if (tid < 64) {
        float l = red[0][tid] + red[1][tid] + red[2][tid] + red[3][tid];
        float m = l;
        #pragma unroll
        for (int d = 1; d < 64; d <<= 1) m = fmaxf(m, __shfl_xor(m, d));
        float ev = __expf(l - m);
        float s = ev;
        #pragma unroll
        for (int d = 1; d < 64; d <<= 1) s += __shfl_xor(s, d);
        e_lds[tid] = ev;
        if (tid == 0) { ms_g[bid * 2] = m; ms_g[bid * 2 + 1] = s; }
    }
    __syncthreads();

    // ---- z partial: zp[q] = sum_t e_t * A_panel[t][q] ----
    // thread: 8 q's (q0..q0+7) x 8 t's (wave's t-group); reduce 8 wave-partials via LDS.
    const int q0 = (tid & 63) * 8;
    const int kt_q = q0 >> 5;
    const int ec = (q0 >> 3) & 3;
    float zq[8];
    #pragma unroll
    for (int k = 0; k < 8; ++k) zq[k] = 0.f;
    #pragma unroll
    for (int ti = 0; ti < 8; ++ti) {
        int t = (tid >> 6) * 8 + ti;
        float ev = e_lds[t];
        short8 av = *(const short8*)&A_p[kt_q][t * 32 + ((ec ^ ((t >> 1) & 3)) << 3)];
        #pragma unroll
        for (int k = 0; k < 8; ++k) zq[k] += ev * bf2f((unsigned short)av[k]);
    }
    __syncthreads();   // done reading sB.B as B; safe to overwrite as zp
    float* zrow = &sB.zp[tid >> 6][0];
    *(float4*)&zrow[q0]     = make_float4(zq[0], zq[1], zq[2], zq[3]);
    *(float4*)&zrow[q0 + 4] = make_float4(zq[4], zq[5], zq[6], zq[7]);
    __syncthreads();
    float z = 0.f;
    #pragma unroll
    for (int w = 0; w < 8; ++w) z += sB.zp[w][tid];
    zp_g[(size_t)bid * 512 + tid] = z;
}

// ---------- combine: merge 32 per-chunk partials per b; write out ----------
__global__ __launch_bounds__(512) void k_comb(const float* __restrict__ zp,
                                              const float* __restrict__ ms,
                                              const float* __restrict__ ip,
                                              float* __restrict__ out) {
    const int b = blockIdx.x, tid = threadIdx.x;
    __shared__ float mm[32], ssv[32];
    if (tid < 32) {
        mm[tid] = ms[(b * 32 + tid) * 2];
        ssv[tid] = ms[(b * 32 + tid) * 2 + 1];
    }
    __syncthreads();
    float M = -1e30f;
    #pragma unroll
    for (int i = 0; i < 32; ++i) M = fmaxf(M, mm[i]);
    float S = 0.f, z = 0.f;
    #pragma unroll 4
    for (int i = 0; i < 32; ++i) {
        float sc = __expf(mm[i] - M);
        S += ssv[i] * sc;
        z += sc * zp[(size_t)(b * 32 + i) * 512 + tid];
    }
    out[b * 1024 + 512 + tid] = z / S;
    out[b * 1024 + tid] = ip[b * 512 + tid];
}

extern "C" void kernel_launch(void* const* d_in, const int* in_sizes, int n_in,
                              void* d_out, int out_size, void* d_ws, size_t ws_size,
                              hipStream_t stream) {
    const float* input_p = (const float*)d_in[0];
    const float* input_q = (const float*)d_in[1];
    const float* h_tm1   = (const float*)d_in[2];
    const float* Wp      = (const float*)d_in[3];
    const float* bp      = (const float*)d_in[4];
    const float* Wq      = (const float*)d_in[5];
    const float* bq      = (const float*)d_in[6];
    const float* Wr      = (const float*)d_in[7];
    const float* br      = (const float*)d_in[8];
    const float* wv      = (const float*)d_in[9];
    float* out = (float*)d_out;

    char* ws = (char*)d_ws;
    unsigned short* Wq_bf = (unsigned short*)ws;            // 512 KB
    float* prq  = (float*)(ws + 512 * 1024);                // 128 KB
    float* ms   = (float*)(ws + 640 * 1024);                // 16 KB (2048 x 2)
    float* zp   = (float*)(ws + 1024 * 1024);               // 4 MB (2048 x 512)

    k_convert8<<<dim3(128), dim3(256), 0, stream>>>(Wq, Wq_bf);
    k_prq<<<dim3(64), dim3(256), 0, stream>>>(input_p, h_tm1, Wp, Wr, bp, bq, br, prq);
    k_fused<<<dim3(2048), dim3(512), 0, stream>>>(input_q, Wq_bf, prq, wv, zp, ms);
    k_comb<<<dim3(64), dim3(512), 0, stream>>>(zp, ms, input_p, out);
}